// Round 12
// baseline (681.411 us; speedup 1.0000x reference)
//
#include <hip/hip_runtime.h>
#include <math.h>
#include <cstddef>

// ---- problem constants ----
#define RTOK 4096
#define CDIM 256
#define NHEAD 16
#define DHEAD 16
#define SEQ 1024
#define BSZ 4

#define ACT_NONE 0
#define ACT_GELU 1

typedef short short8 __attribute__((ext_vector_type(8)));
typedef float f32x4  __attribute__((ext_vector_type(4)));
typedef _Float16 half8 __attribute__((ext_vector_type(8)));
typedef _Float16 half4 __attribute__((ext_vector_type(4)));

__device__ __forceinline__ float gelu_erf(float x) {
    return 0.5f * x * (1.0f + erff(x * 0.70710678118654752f));
}
__device__ __forceinline__ unsigned short f2b(float f) {
    unsigned u = __float_as_uint(f);
    unsigned r = (u + 0x7FFFu + ((u >> 16) & 1u)) >> 16;
    return (unsigned short)r;
}
__device__ __forceinline__ float b2f(unsigned short u) {
    return __uint_as_float((unsigned)u << 16);
}
// async global->LDS, 16B per lane. LDS dest must be wave-uniform base + lane*16.
__device__ __forceinline__ void gld16(const unsigned short* g, unsigned short* l) {
    __builtin_amdgcn_global_load_lds(
        (const __attribute__((address_space(1))) unsigned int*)g,
        (__attribute__((address_space(3))) unsigned int*)l, 16, 0, 0);
}
// node-mix softmax weight widx of node_w[0:cnt]/0.01
__device__ __forceinline__ float node_wsel(const float* nwp, int cnt, int widx) {
    float ww[8];
    float mx = -1e30f;
    for (int t = 0; t < cnt; ++t) { ww[t] = nwp[t] * 100.0f; mx = fmaxf(mx, ww[t]); }
    float ssum = 0.0f;
    for (int t = 0; t < cnt; ++t) { ww[t] = expf(ww[t] - mx); ssum += ww[t]; }
    return ww[widx] / ssum;
}

// ---------------------------------------------------------------------------
// Setup union dispatch: weight convert+transpose (9 segments) + patch-embed.
// blocks [0, cum9): wtrans ; blocks [cum9, cum9+4096): embed rows.
// ---------------------------------------------------------------------------
struct WtSeg { const float* in; unsigned short* out; int K, N, ntx, tpz, zin, zout; };
struct WtTab { WtSeg s[9]; int cum[10]; };

__global__ __launch_bounds__(256) void setup_kernel(
    WtTab tab,
    const float* __restrict__ x, const int* __restrict__ mask_index,
    const float* __restrict__ Wp, const float* __restrict__ bp,
    const float* __restrict__ cls,
    float* __restrict__ Fout, unsigned short* __restrict__ Fbout)
{
    __shared__ float tt[32][33];
    __shared__ float xs[12];
    if ((int)blockIdx.x < tab.cum[9]) {
        int g = blockIdx.x;
        int si = 0;
        #pragma unroll
        for (int i = 0; i < 8; ++i) if (g >= tab.cum[i + 1]) si = i + 1;
        WtSeg sg = tab.s[si];
        int t = g - tab.cum[si];
        int z = t / sg.tpz, r = t % sg.tpz;
        int kb = (r % sg.ntx) * 32, nb = (r / sg.ntx) * 32;
        const float* in = sg.in + (size_t)z * sg.zin;
        unsigned short* out = sg.out + (size_t)z * sg.zout;
        int tx = threadIdx.x & 31, ty = threadIdx.x >> 5;   // 32 x 8
        #pragma unroll
        for (int rr = 0; rr < 4; ++rr) {
            int kk = ty * 4 + rr;
            tt[kk][tx] = in[(size_t)(kb + kk) * sg.N + nb + tx];
        }
        __syncthreads();
        #pragma unroll
        for (int rr = 0; rr < 4; ++rr) {
            int nn = ty * 4 + rr;
            out[(size_t)(nb + nn) * sg.K + kb + tx] = f2b(tt[tx][nn]);
        }
    } else {
        int row = blockIdx.x - tab.cum[9];
        int b = row >> 10;
        int c = threadIdx.x;
        int idx = mask_index[row];
        if (idx == 0) {
            float v = cls[c];
            Fout[(size_t)row * 256 + c] = v;
            Fbout[(size_t)row * 256 + c] = f2b(v);
            return;
        }
        int p  = idx - 1;
        int ph = p >> 6, pw = p & 63;
        if (c < 12) {
            int ch = c >> 2, r = (c >> 1) & 1, q = c & 1;
            xs[c] = x[(((size_t)b * 3 + ch) * 128 + (ph * 2 + r)) * 128 + (pw * 2 + q)];
        }
        __syncthreads();
        float acc = bp[c];
        #pragma unroll
        for (int t = 0; t < 12; ++t) acc += xs[t] * Wp[c * 12 + t];
        int part = c >> 6, cc = c & 63;
        double omega = exp((double)cc * -0.14391156831212787);
        double posv  = (part < 2) ? (double)pw : (double)ph;
        double a     = posv * omega;
        double e     = ((part & 1) == 0) ? sin(a) : cos(a);
        float v = acc + (float)e;
        Fout[(size_t)row * 256 + c] = v;
        Fbout[(size_t)row * 256 + c] = f2b(v);
    }
}

// ---------------------------------------------------------------------------
// bf16 MFMA GEMM, BK=64, async global_load_lds(16B) staging into DENSE
// XOR-swizzled LDS, double-buffered (one barrier per 64-K slab). K % 128 == 0.
// XCD-aware block remap.
// BMODE: 0 none, 1 bf16 Cb, 2 f16 Cb.
// SPLIT: col<N0 -> fp32 C side (stride N0, bias), col>=N0 -> Cb bf16.
// NW: 0 none; 2: v = wsel*v + Rsd; 4: v = wsel*v + Rsd + wselB*O1p.
// ---------------------------------------------------------------------------
template<int MT, int ACT, bool RES, bool FOUT, int BMODE, bool SPLIT, int NW>
__global__ __launch_bounds__(256) void gemm_mfma(
    const unsigned short* __restrict__ A, const unsigned short* __restrict__ Bt,
    const float* __restrict__ bias, const float* __restrict__ bias1,
    const float* __restrict__ Rsd,
    float* __restrict__ C, unsigned short* __restrict__ Cb,
    int M, int N, int K, int N0,
    const float* __restrict__ nwp, int ncnt, int widx,
    const float* __restrict__ O1p, int widxB)
{
    constexpr int BM = 64 * MT;
    __shared__ __align__(16) unsigned short As0[BM * 64];
    __shared__ __align__(16) unsigned short As1[BM * 64];
    __shared__ __align__(16) unsigned short Bs0[64 * 64];
    __shared__ __align__(16) unsigned short Bs1[64 * 64];
    int tid = threadIdx.x;
    int w = tid >> 6, lane = tid & 63;
    int l15 = lane & 15, q = lane >> 4;

    int gx = gridDim.x, gy = gridDim.y;
    int L = blockIdx.x + gx * blockIdx.y;
    int xcd = L & 7, j = L >> 3;
    int by = xcd * (gy >> 3) + j / gx;
    int bx = j - (j / gx) * gx;
    int row0 = by * BM, col0 = bx * 64;

    f32x4 acc[MT][4];
    #pragma unroll
    for (int mt = 0; mt < MT; ++mt)
        #pragma unroll
        for (int nt = 0; nt < 4; ++nt)
            acc[mt][nt] = (f32x4){0.f, 0.f, 0.f, 0.f};

#define G_ISSUE(AS, BS, KB)                                                   \
    do {                                                                      \
        _Pragma("unroll")                                                     \
        for (int t = 0; t < 2 * MT; ++t) {                                    \
            int slot = tid + t * 256;                                         \
            int r = slot >> 3;                                                \
            int s = (slot & 7) ^ (r & 7);                                     \
            gld16(A + (size_t)(row0 + r) * K + (KB) + s * 8, &AS[slot * 8]);  \
        }                                                                     \
        _Pragma("unroll")                                                     \
        for (int t = 0; t < 2; ++t) {                                         \
            int slot = tid + t * 256;                                         \
            int r = slot >> 3;                                                \
            int s = (slot & 7) ^ (r & 7);                                     \
            gld16(Bt + (size_t)(col0 + r) * K + (KB) + s * 8, &BS[slot * 8]); \
        }                                                                     \
    } while (0)

#define G_COMPUTE(AS, BS)                                                     \
    do {                                                                      \
        _Pragma("unroll")                                                     \
        for (int hh = 0; hh < 2; ++hh) {                                      \
            short8 af[MT];                                                    \
            _Pragma("unroll")                                                 \
            for (int mt = 0; mt < MT; ++mt) {                                 \
                int R = w * 16 * MT + mt * 16 + l15;                          \
                int c = hh * 4 + q;                                           \
                af[mt] = *(const short8*)&AS[R * 64 + ((c ^ (R & 7)) << 3)];  \
            }                                                                 \
            _Pragma("unroll")                                                 \
            for (int nt = 0; nt < 4; ++nt) {                                  \
                int R = nt * 16 + l15;                                        \
                int c = hh * 4 + q;                                           \
                short8 bf = *(const short8*)&BS[R * 64 + ((c ^ (R & 7)) << 3)];\
                _Pragma("unroll")                                             \
                for (int mt = 0; mt < MT; ++mt)                               \
                    acc[mt][nt] = __builtin_amdgcn_mfma_f32_16x16x32_bf16(    \
                        af[mt], bf, acc[mt][nt], 0, 0, 0);                    \
            }                                                                 \
        }                                                                     \
    } while (0)

    G_ISSUE(As0, Bs0, 0);
    for (int kb = 0; kb < K; kb += 128) {
        __syncthreads();
        G_ISSUE(As1, Bs1, kb + 64);
        G_COMPUTE(As0, Bs0);
        __syncthreads();
        if (kb + 128 < K) G_ISSUE(As0, Bs0, kb + 128);
        G_COMPUTE(As1, Bs1);
    }
#undef G_ISSUE
#undef G_COMPUTE

    float wsel = 0.0f, wselB = 0.0f;
    if (NW > 0) wsel = node_wsel(nwp, ncnt, widx);
    if (NW == 4) wselB = node_wsel(nwp, ncnt, widxB);

    #pragma unroll
    for (int mt = 0; mt < MT; ++mt) {
        #pragma unroll
        for (int nt = 0; nt < 4; ++nt) {
            #pragma unroll
            for (int reg = 0; reg < 4; ++reg) {
                int row = row0 + w * 16 * MT + mt * 16 + q * 4 + reg;
                int col = col0 + nt * 16 + l15;
                if (SPLIT) {
                    float v = acc[mt][nt][reg] +
                              (col < N0 ? bias[col] : bias1[col - N0]);
                    if (ACT == ACT_GELU) v = gelu_erf(v);
                    if (col < N0) C[(size_t)row * N0 + col] = v;
                    else Cb[(size_t)row * (N - N0) + (col - N0)] = f2b(v);
                } else {
                    float v = acc[mt][nt][reg] + bias[col];
                    if (ACT == ACT_GELU) v = gelu_erf(v);
                    if (NW == 2) v = wsel * v + Rsd[(size_t)row * N + col];
                    else if (NW == 4) v = wsel * v + Rsd[(size_t)row * N + col]
                                        + wselB * O1p[(size_t)row * N + col];
                    else if (RES) v += Rsd[(size_t)row * N + col];
                    if (FOUT) C[(size_t)row * N + col] = v;
                    if (BMODE == 1) Cb[(size_t)row * N + col] = f2b(v);
                    if (BMODE == 2) {
                        _Float16 hv = (_Float16)v;
                        Cb[(size_t)row * N + col] = *(unsigned short*)&hv;
                    }
                }
            }
        }
    }
}

// ---------------------------------------------------------------------------
// Union dispatch: cm1 GEMM (640 blocks; M=4096 N=1280 K=256, SPLIT at 256:
// fp32 side -> O1 = gelu(xl@conv+b), bf16 side -> MIDU = gelu(xl@mlp1+b))
// + chanattn/node-mix-init (4096 blocks; MIX = hist + xl-terms + w*o2).
// The w*o1 term is added later in mlp2's NW=4 epilogue.
// ---------------------------------------------------------------------------
__global__ __launch_bounds__(256) void cm1chan_kernel(
    const unsigned short* __restrict__ A, const unsigned short* __restrict__ Bt,
    const float* __restrict__ biasC, const float* __restrict__ biasM,
    float* __restrict__ O1, unsigned short* __restrict__ MIDU,
    const float* __restrict__ xl,
    const float* f0, const float* f1, const float* f2,
    const float* __restrict__ ca1w, const float* __restrict__ ca1b,
    const float* __restrict__ ca2w, const float* __restrict__ ca2b,
    const float* __restrict__ node_w, int cnt,
    float* __restrict__ MIX)
{
    __shared__ __align__(16) unsigned short As0[128 * 64];
    __shared__ __align__(16) unsigned short As1[128 * 64];
    __shared__ __align__(16) unsigned short Bs0[64 * 64];
    __shared__ __align__(16) unsigned short Bs1[64 * 64];
    __shared__ float xs[256];
    __shared__ float sm16[16];
    int tid = threadIdx.x;

    if ((int)blockIdx.x < 640) {
        // ---- GEMM path ----
        const int K = 256, N0 = 256;
        int w = tid >> 6, lane = tid & 63;
        int l15 = lane & 15, q = lane >> 4;
        int L = blockIdx.x;
        int xcd = L & 7, j = L >> 3;
        int by = xcd * 4 + j / 20;
        int bx = j - (j / 20) * 20;
        int row0 = by * 128, col0 = bx * 64;

        f32x4 acc[2][4];
        #pragma unroll
        for (int mt = 0; mt < 2; ++mt)
            #pragma unroll
            for (int nt = 0; nt < 4; ++nt)
                acc[mt][nt] = (f32x4){0.f, 0.f, 0.f, 0.f};

#define C_ISSUE(AS, BS, KB)                                                   \
    do {                                                                      \
        _Pragma("unroll")                                                     \
        for (int t = 0; t < 4; ++t) {                                         \
            int slot = tid + t * 256;                                         \
            int r = slot >> 3;                                                \
            int s = (slot & 7) ^ (r & 7);                                     \
            gld16(A + (size_t)(row0 + r) * K + (KB) + s * 8, &AS[slot * 8]);  \
        }                                                                     \
        _Pragma("unroll")                                                     \
        for (int t = 0; t < 2; ++t) {                                         \
            int slot = tid + t * 256;                                         \
            int r = slot >> 3;                                                \
            int s = (slot & 7) ^ (r & 7);                                     \
            gld16(Bt + (size_t)(col0 + r) * K + (KB) + s * 8, &BS[slot * 8]); \
        }                                                                     \
    } while (0)

#define C_COMPUTE(AS, BS)                                                     \
    do {                                                                      \
        _Pragma("unroll")                                                     \
        for (int hh = 0; hh < 2; ++hh) {                                      \
            short8 af[2];                                                     \
            _Pragma("unroll")                                                 \
            for (int mt = 0; mt < 2; ++mt) {                                  \
                int R = w * 32 + mt * 16 + l15;                               \
                int c = hh * 4 + q;                                           \
                af[mt] = *(const short8*)&AS[R * 64 + ((c ^ (R & 7)) << 3)];  \
            }                                                                 \
            _Pragma("unroll")                                                 \
            for (int nt = 0; nt < 4; ++nt) {                                  \
                int R = nt * 16 + l15;                                        \
                int c = hh * 4 + q;                                           \
                short8 bf = *(const short8*)&BS[R * 64 + ((c ^ (R & 7)) << 3)];\
                _Pragma("unroll")                                             \
                for (int mt = 0; mt < 2; ++mt)                                \
                    acc[mt][nt] = __builtin_amdgcn_mfma_f32_16x16x32_bf16(    \
                        af[mt], bf, acc[mt][nt], 0, 0, 0);                    \
            }                                                                 \
        }                                                                     \
    } while (0)

        C_ISSUE(As0, Bs0, 0);
        for (int kb = 0; kb < K; kb += 128) {
            __syncthreads();
            C_ISSUE(As1, Bs1, kb + 64);
            C_COMPUTE(As0, Bs0);
            __syncthreads();
            if (kb + 128 < K) C_ISSUE(As0, Bs0, kb + 128);
            C_COMPUTE(As1, Bs1);
        }
#undef C_ISSUE
#undef C_COMPUTE

        #pragma unroll
        for (int mt = 0; mt < 2; ++mt) {
            #pragma unroll
            for (int nt = 0; nt < 4; ++nt) {
                #pragma unroll
                for (int reg = 0; reg < 4; ++reg) {
                    int row = row0 + w * 32 + mt * 16 + q * 4 + reg;
                    int col = col0 + nt * 16 + l15;
                    if (col < N0) {
                        float v = gelu_erf(acc[mt][nt][reg] + biasC[col]);
                        O1[(size_t)row * 256 + col] = v;
                    } else {
                        float v = gelu_erf(acc[mt][nt][reg] + biasM[col - 256]);
                        MIDU[(size_t)row * 1024 + (col - 256)] = f2b(v);
                    }
                }
            }
        }
    } else {
        // ---- chanattn + node-mix init path ----
        size_t row = blockIdx.x - 640;
        xs[tid] = xl[row * 256 + tid];
        __syncthreads();

        int h = tid >> 4, part = tid & 15;
        float p = 0.f;
        #pragma unroll
        for (int i = 0; i < 16; ++i)
            p += xs[part * 16 + i] * ca1w[(part * 16 + i) * 16 + h];
        p += __shfl_down(p, 8, 16);
        p += __shfl_down(p, 4, 16);
        p += __shfl_down(p, 2, 16);
        p += __shfl_down(p, 1, 16);
        if (part == 0) sm16[h] = fmaxf(p + ca1b[h], 0.0f);
        __syncthreads();

        float g = ca2b[tid];
        #pragma unroll
        for (int hh = 0; hh < 16; ++hh) g += sm16[hh] * ca2w[hh * 256 + tid];
        g = 1.0f / (1.0f + expf(-g));
        float o2 = g * xs[tid];

        float ww[8];
        float mx = -1e30f;
        for (int t = 0; t < cnt; ++t) { ww[t] = node_w[t] * 100.0f; mx = fmaxf(mx, ww[t]); }
        float ssum = 0.0f;
        for (int t = 0; t < cnt; ++t) { ww[t] = expf(ww[t] - mx); ssum += ww[t]; }
        float inv = 1.0f / ssum;
        int jj = cnt - 5;
        float acc2 = (ww[jj] + ww[jj + 3]) * inv * xs[tid] + ww[jj + 2] * inv * o2;
        const float* fs[3] = {f0, f1, f2};
        for (int t = 0; t < jj; ++t) acc2 += ww[t] * inv * fs[t][row * 256 + tid];
        MIX[row * 256 + tid] = acc2;
    }
}

// ---------------------------------------------------------------------------
// LayerNorm N=256, one WAVE per row (4 rows/block). fp32->bf16.
// ---------------------------------------------------------------------------
__global__ __launch_bounds__(256) void ln256_kernel(
    const float* __restrict__ in, unsigned short* __restrict__ outb,
    const float* __restrict__ g, const float* __restrict__ bb)
{
    int row = blockIdx.x * 4 + (threadIdx.x >> 6);
    int lane = threadIdx.x & 63;
    f32x4 xv = *(const f32x4*)(in + (size_t)row * 256 + lane * 4);
    float s = xv[0] + xv[1] + xv[2] + xv[3];
    #pragma unroll
    for (int off = 1; off < 64; off <<= 1) s += __shfl_xor(s, off, 64);
    float mu = s * (1.0f / 256.0f);
    float d0 = xv[0]-mu, d1 = xv[1]-mu, d2 = xv[2]-mu, d3 = xv[3]-mu;
    float s2 = d0*d0 + d1*d1 + d2*d2 + d3*d3;
    #pragma unroll
    for (int off = 1; off < 64; off <<= 1) s2 += __shfl_xor(s2, off, 64);
    float rstd = rsqrtf(s2 * (1.0f / 256.0f) + 1e-5f);
    f32x4 gv = *(const f32x4*)(g + lane * 4);
    f32x4 bv = *(const f32x4*)(bb + lane * 4);
    ushort4 o;
    o.x = f2b(d0 * rstd * gv[0] + bv[0]);
    o.y = f2b(d1 * rstd * gv[1] + bv[1]);
    o.z = f2b(d2 * rstd * gv[2] + bv[2]);
    o.w = f2b(d3 * rstd * gv[3] + bv[3]);
    *(ushort4*)(outb + (size_t)row * 256 + lane * 4) = o;
}

// ---------------------------------------------------------------------------
// LayerNorm N=2048, one WAVE per row (4 rows/block), bf16->bf16, vectorized.
// ---------------------------------------------------------------------------
__global__ __launch_bounds__(256) void ln2048w_kernel(
    const unsigned short* __restrict__ in, unsigned short* __restrict__ outb,
    const float* __restrict__ g, const float* __restrict__ bb)
{
    int row = blockIdx.x * 4 + (threadIdx.x >> 6);
    int lane = threadIdx.x & 63;
    const unsigned short* xr = in + (size_t)row * 2048 + lane * 32;
    unsigned short v[32];
    *(uint4*)&v[0]  = *(const uint4*)&xr[0];
    *(uint4*)&v[8]  = *(const uint4*)&xr[8];
    *(uint4*)&v[16] = *(const uint4*)&xr[16];
    *(uint4*)&v[24] = *(const uint4*)&xr[24];
    float s = 0.f;
    #pragma unroll
    for (int i = 0; i < 32; ++i) s += b2f(v[i]);
    #pragma unroll
    for (int off = 1; off < 64; off <<= 1) s += __shfl_xor(s, off, 64);
    float mu = s * (1.0f / 2048.0f);
    float s2 = 0.f;
    #pragma unroll
    for (int i = 0; i < 32; ++i) { float d = b2f(v[i]) - mu; s2 += d * d; }
    #pragma unroll
    for (int off = 1; off < 64; off <<= 1) s2 += __shfl_xor(s2, off, 64);
    float rstd = rsqrtf(s2 * (1.0f / 2048.0f) + 1e-5f);
    unsigned short o[32];
    #pragma unroll
    for (int i = 0; i < 32; ++i)
        o[i] = f2b((b2f(v[i]) - mu) * rstd * g[lane * 32 + i] + bb[lane * 32 + i]);
    unsigned short* op = outb + (size_t)row * 2048 + lane * 32;
    *(uint4*)&op[0]  = *(const uint4*)&o[0];
    *(uint4*)&op[8]  = *(const uint4*)&o[8];
    *(uint4*)&op[16] = *(const uint4*)&o[16];
    *(uint4*)&op[24] = *(const uint4*)&o[24];
}

// ---------------------------------------------------------------------------
// Attention prep: LN Q (x scale x log2e) and K once; transpose V.
// Qp/Kp: [bh][tok][16] f16 ; Vp: [bh][d][1024] f16.
// ---------------------------------------------------------------------------
__global__ __launch_bounds__(256) void attn_prep(
    const unsigned short* __restrict__ qkvh,
    const float* __restrict__ nqg, const float* __restrict__ nqb,
    const float* __restrict__ nkg, const float* __restrict__ nkb,
    unsigned short* __restrict__ Qph, unsigned short* __restrict__ Kph,
    unsigned short* __restrict__ Vph)
{
    int b = blockIdx.x >> 6;
    int tokbase = (blockIdx.x & 63) * 16;
    int tid = threadIdx.x;
    int tl = tid >> 4, h = tid & 15;
    int tok = tokbase + tl;
    const _Float16* qkv = (const _Float16*)qkvh;
    const _Float16* rowp = qkv + ((size_t)(b * 1024 + tok)) * 768;
    _Float16* Qp = (_Float16*)Qph;
    _Float16* Kp = (_Float16*)Kph;
    _Float16* Vp = (_Float16*)Vph;
    const float QSC = 0.25f * 1.44269504088896340736f;  // 1/sqrt(16)*log2(e)

    __shared__ _Float16 vt[16][16][17];   // [tok][h][d]

    {
        half8 a0 = *(const half8*)(rowp + h * 16);
        half8 a1 = *(const half8*)(rowp + h * 16 + 8);
        float v[16];
        #pragma unroll
        for (int e = 0; e < 8; ++e) { v[e] = (float)a0[e]; v[8 + e] = (float)a1[e]; }
        float mu = 0.f;
        #pragma unroll
        for (int d = 0; d < 16; ++d) mu += v[d];
        mu *= (1.0f / 16.0f);
        float var = 0.f;
        #pragma unroll
        for (int d = 0; d < 16; ++d) { float t = v[d] - mu; var += t * t; }
        var *= (1.0f / 16.0f);
        float rstd = rsqrtf(var + 1e-5f);
        half8 o0, o1;
        #pragma unroll
        for (int e = 0; e < 8; ++e) {
            o0[e] = (_Float16)(((v[e] - mu) * rstd * nqg[e] + nqb[e]) * QSC);
            o1[e] = (_Float16)(((v[8+e] - mu) * rstd * nqg[8+e] + nqb[8+e]) * QSC);
        }
        _Float16* qo = Qp + ((size_t)(b * 16 + h) * 1024 + tok) * 16;
        *(half8*)qo = o0;
        *(half8*)(qo + 8) = o1;
    }
    {
        half8 a0 = *(const half8*)(rowp + 256 + h * 16);
        half8 a1 = *(const half8*)(rowp + 256 + h * 16 + 8);
        float v[16];
        #pragma unroll
        for (int e = 0; e < 8; ++e) { v[e] = (float)a0[e]; v[8 + e] = (float)a1[e]; }
        float mu = 0.f;
        #pragma unroll
        for (int d = 0; d < 16; ++d) mu += v[d];
        mu *= (1.0f / 16.0f);
        float var = 0.f;
        #pragma unroll
        for (int d = 0; d < 16; ++d) { float t = v[d] - mu; var += t * t; }
        var *= (1.0f / 16.0f);
        float rstd = rsqrtf(var + 1e-5f);
        half8 o0, o1;
        #pragma unroll
        for (int e = 0; e < 8; ++e) {
            o0[e] = (_Float16)((v[e] - mu) * rstd * nkg[e] + nkb[e]);
            o1[e] = (_Float16)((v[8+e] - mu) * rstd * nkg[8+e] + nkb[8+e]);
        }
        _Float16* ko = Kp + ((size_t)(b * 16 + h) * 1024 + tok) * 16;
        *(half8*)ko = o0;
        *(half8*)(ko + 8) = o1;
    }
    {
        half8 a0 = *(const half8*)(rowp + 512 + h * 16);
        half8 a1 = *(const half8*)(rowp + 512 + h * 16 + 8);
        #pragma unroll
        for (int e = 0; e < 8; ++e) { vt[tl][h][e] = a0[e]; vt[tl][h][8 + e] = a1[e]; }
    }
    __syncthreads();
    {
        int h2 = tid >> 4, d = tid & 15;
        half8 o0, o1;
        #pragma unroll
        for (int t = 0; t < 8; ++t) { o0[t] = vt[t][h2][d]; o1[t] = vt[8 + t][h2][d]; }
        _Float16* vo = Vp + ((size_t)(b * 16 + h2) * 16 + d) * 1024 + tokbase;
        *(half8*)vo = o0;
        *(half8*)(vo + 8) = o1;
    }
}

// ---------------------------------------------------------------------------
// MFMA flash attention v4: K/V double-buffered (one barrier per kt), QK^T via
// mfma_f32_16x16x16_f16 (K=16 exactly -> no zero pads), PV via 16x16x32.
// 64-query blocks (grid 16x16x4), 4 waves x 16 q. LDS ~35.5 KB -> 4 blk/CU.
// ---------------------------------------------------------------------------
__global__ __launch_bounds__(256) void attn_kernel(
    const unsigned short* __restrict__ Qph, const unsigned short* __restrict__ Kph,
    const unsigned short* __restrict__ Vph,
    unsigned short* __restrict__ outb)          // [4096,256] bf16
{
    int qt = blockIdx.x, h = blockIdx.y, b = blockIdx.z;
    int bh = b * 16 + h;
    int tid = threadIdx.x;
    int w = tid >> 6, lane = tid & 63;
    int l15 = lane & 15, quad = lane >> 4;
    const _Float16* Qp = (const _Float16*)Qph + (size_t)bh * 1024 * 16;
    const _Float16* Kp = (const _Float16*)Kph + (size_t)bh * 1024 * 16;
    const _Float16* Vp = (const _Float16*)Vph + (size_t)bh * 16 * 1024;

    __shared__ __align__(16) _Float16 Qs[64 * 16];
    __shared__ __align__(16) _Float16 Kb[2][128 * 16];
    __shared__ __align__(16) _Float16 Vt[2][16 * 136];
    __shared__ __align__(16) _Float16 Ps[4][16 * 136];

    // stage Q (64 rows x 16 halves, dense)
    if (tid < 128) {
        int r = tid >> 1, part = tid & 1;
        *(uint4*)&Qs[r * 16 + part * 8] =
            *(const uint4*)(Qp + (size_t)(qt * 64 + r) * 16 + part * 8);
    }

    uint4 r0, r1;
#define A_LOAD(KT)                                                            \
    do {                                                                      \
        if (tid < 128) {                                                      \
            const uint4* src = (const uint4*)(Kp + (size_t)((KT) * 128 + tid) * 16); \
            r0 = src[0]; r1 = src[1];                                         \
        } else {                                                              \
            int t = tid - 128, d = t >> 3, k8 = t & 7;                        \
            const uint4* src = (const uint4*)(Vp + (size_t)d * 1024 + (KT) * 128 + k8 * 16); \
            r0 = src[0]; r1 = src[1];                                         \
        }                                                                     \
    } while (0)
#define A_WRITE(BUF)                                                          \
    do {                                                                      \
        if (tid < 128) {                                                      \
            *(uint4*)&Kb[BUF][tid * 16 + 0] = r0;                             \
            *(uint4*)&Kb[BUF][tid * 16 + 8] = r1;                             \
        } else {                                                              \
            int t = tid - 128, d = t >> 3, k8 = t & 7;                        \
            *(uint4*)&Vt[BUF][d * 136 + k8 * 16 + 0] = r0;                    \
            *(uint4*)&Vt[BUF][d * 136 + k8 * 16 + 8] = r1;                    \
        }                                                                     \
    } while (0)

    A_LOAD(0);
    A_WRITE(0);
    __syncthreads();                // Qs + buf0 visible

    half4 bq = *(const half4*)&Qs[(w * 16 + l15) * 16 + quad * 4];
    float mst = -1e30f, lst = 0.f;
    f32x4 acco = (f32x4){0.f, 0.f, 0.f, 0.f};

    int p = 0;
    for (int kt = 0; kt < 8; ++kt) {
        if (kt < 7) A_LOAD(kt + 1);
        if (kt > 0) __syncthreads();   // buf[p] writes visible; readers of buf[1-p] done

        // ---- S^T tile: 128 keys x 16 queries per wave (K=16 exact) ----
        f32x4 sacc[8];
        #pragma unroll
        for (int ni = 0; ni < 8; ++ni) {
            half4 ak = *(const half4*)&Kb[p][(ni * 16 + l15) * 16 + quad * 4];
            sacc[ni] = __builtin_amdgcn_mfma_f32_16x16x16f16(
                ak, bq, (f32x4){0.f, 0.f, 0.f, 0.f}, 0, 0, 0);
        }
        half8 bv[4];
        #pragma unroll
        for (int c = 0; c < 4; ++c)
            bv[c] = *(const half8*)&Vt[p][l15 * 136 + c * 32 + quad * 8];

        // ---- online softmax for the wave's 16 queries (q = l15) ----
        float rm = sacc[0][0];
        #pragma unroll
        for (int ni = 0; ni < 8; ++ni)
            #pragma unroll
            for (int reg = 0; reg < 4; ++reg)
                rm = fmaxf(rm, sacc[ni][reg]);
        rm = fmaxf(rm, __shfl_xor(rm, 16, 64));
        rm = fmaxf(rm, __shfl_xor(rm, 32, 64));
        float mn  = fmaxf(mst, rm);
        float cor = exp2f(mst - mn);
        mst = mn;
        lst *= cor;
        #pragma unroll
        for (int reg = 0; reg < 4; ++reg) {
            float cR = __shfl(cor, (lane & 48) + quad * 4 + reg, 64);
            acco[reg] *= cR;
        }
        float lsum = 0.f;
        #pragma unroll
        for (int ni = 0; ni < 8; ++ni) {
            half4 ph;
            #pragma unroll
            for (int reg = 0; reg < 4; ++reg) {
                float pp = exp2f(sacc[ni][reg] - mn);
                lsum += pp;
                ph[reg] = (_Float16)pp;
            }
            *(half4*)&Ps[w][l15 * 136 + ni * 16 + quad * 4] = ph;
        }
        lsum += __shfl_xor(lsum, 16, 64);
        lsum += __shfl_xor(lsum, 32, 64);
        lst += lsum;

        // ---- PV (Ps wave-private; 16x16x32) ----
        #pragma unroll
        for (int c = 0; c < 4; ++c) {
            half8 p0 = *(const half8*)&Ps[w][l15 * 136 + c * 32 + quad * 8];
            acco = __builtin_amdgcn_mfma_f32_16x16x32_f16(p0, bv[c], acco, 0, 0, 0);
        }

        if (kt < 7) A_WRITE(1 - p);
        p ^= 1;
    }
#undef A_LOAD
#undef A_WRITE

    #pragma unroll
    for (int reg = 0; reg < 4; ++reg) {
        float lR = __shfl(lst, (lane & 48) + quad * 4 + reg, 64);
        float o = acco[reg] / lR;
        int row = b * 1024 + qt * 64 + w * 16 + quad * 4 + reg;
        outb[(size_t)row * 256 + h * 16 + l15] = f2b(o);
    }
}

// ---------------------------------------------------------------------------
extern "C" void kernel_launch(void* const* d_in, const int* in_sizes, int n_in,
                              void* d_out, int out_size, void* d_ws, size_t ws_size,
                              hipStream_t stream)
{
    const float* x          = (const float*)d_in[0];
    const int*   mask_index = (const int*)  d_in[1];
    const float* Wp         = (const float*)d_in[2];
    const float* bp         = (const float*)d_in[3];
    const float* cls        = (const float*)d_in[4];
    const float* qkv_w      = (const float*)d_in[5];
    const float* qkv_b      = (const float*)d_in[6];
    const float* proj_w     = (const float*)d_in[7];
    const float* proj_b     = (const float*)d_in[8];
    const float* nq_g       = (const float*)d_in[9];
    const float* nq_b       = (const float*)d_in[10];
    const float* nk_g       = (const float*)d_in[11];
    const float* nk_b       = (const float*)d_in[12];
    const float* conv_w     = (const float*)d_in[13];
    const float* conv_b     = (const float*)d_in[14];
    const float* ca1_w      = (const float*)d_in[15];
    const float* ca1_b      = (const float*)d_in[16];
    const float* ca2_w      = (const float*)d_in[17];
    const float* ca2_b      = (const float*)d_in[18];
    const float* mlp1_w     = (const float*)d_in[19];
    const float* mlp1_b     = (const float*)d_in[20];
    const float* mlp2_w     = (const float*)d_in[21];
    const float* mlp2_b     = (const float*)d_in[22];
    const float* node_w     = (const float*)d_in[23];
    const float* ln0_g      = (const float*)d_in[24];
    const float* ln0_b      = (const float*)d_in[25];
    const float* h1_w       = (const float*)d_in[26];
    const float* h1_b       = (const float*)d_in[27];
    const float* ln1_g      = (const float*)d_in[28];
    const float* ln1_b      = (const float*)d_in[29];
    const float* h2_w       = (const float*)d_in[30];
    const float* h2_b       = (const float*)d_in[31];
    const float* ln2_g      = (const float*)d_in[32];
    const float* ln2_b      = (const float*)d_in[33];
    const float* h3_w       = (const float*)d_in[34];
    const float* h3_b       = (const float*)d_in[35];
    const float* pr_w       = (const float*)d_in[36];
    const float* pr_b       = (const float*)d_in[37];
    float* out = (float*)d_out;

    // ---- workspace layout ----
    char* base = (char*)d_ws;
    size_t off = 0;
    auto alloc = [&](size_t bytes) -> char* {
        char* p = base + off;
        off += (bytes + 255) & ~(size_t)255;
        return p;
    };
    const size_t RC = (size_t)RTOK * CDIM;
    float* F[5];
    unsigned short* Fb[5];
    for (int i = 0; i < 5; ++i) F[i] = (float*)alloc(RC * 4);
    for (int i = 0; i < 5; ++i) Fb[i] = (unsigned short*)alloc(RC * 2);
    float* MIX = (float*)alloc(RC * 4);
    float* O1  = (float*)alloc(RC * 4);
    unsigned short* MIXb = (unsigned short*)alloc(RC * 2);
    unsigned short* AOb  = (unsigned short*)alloc(RC * 2);
    unsigned short* BIGH = (unsigned short*)alloc((size_t)RTOK * 768 * 2);  // qkv f16
    unsigned short* Qp   = (unsigned short*)alloc(RC * 2);
    unsigned short* Kp   = (unsigned short*)alloc(RC * 2);
    unsigned short* Vp   = (unsigned short*)alloc(RC * 2);
    unsigned short* H1b  = (unsigned short*)alloc((size_t)RTOK * 2048 * 2);
    unsigned short* MIDU = (unsigned short*)alloc((size_t)RTOK * 2048 * 2);
    unsigned short* L0b  = (unsigned short*)alloc(RC * 2);
    unsigned short* L2b  = (unsigned short*)alloc(RC * 2);
    unsigned short* H3b  = (unsigned short*)alloc((size_t)RTOK * 2048 * 2);
    // bf16 transposed weights; conv||mlp1 concatenated to [1280,256] per layer
    unsigned short* cm1b  = (unsigned short*)alloc((size_t)4 * 1280 * 256 * 2);
    unsigned short* qkvb  = (unsigned short*)alloc((size_t)4 * 768 * 256 * 2);
    unsigned short* projb = (unsigned short*)alloc((size_t)4 * 256 * 256 * 2);
    unsigned short* mlp2b = (unsigned short*)alloc((size_t)4 * 256 * 1024 * 2);
    unsigned short* h1b   = (unsigned short*)alloc((size_t)2048 * 256 * 2);
    unsigned short* h2b   = (unsigned short*)alloc((size_t)256 * 2048 * 2);
    unsigned short* h3b   = (unsigned short*)alloc((size_t)2048 * 256 * 2);
    unsigned short* prb   = (unsigned short*)alloc((size_t)512 * 2048 * 2);

    // ---- setup: weight conversion + embed in ONE dispatch ----
    {
        WtTab tab;
        int c = 0, idx = 0;
        auto seg = [&](const float* in, unsigned short* outp, int K, int N,
                       int z, int zin, int zout) {
            WtSeg s; s.in = in; s.out = outp; s.K = K; s.N = N;
            s.ntx = K / 32; s.tpz = (K / 32) * (N / 32);
            s.zin = zin; s.zout = zout;
            tab.s[idx] = s; tab.cum[idx] = c;
            c += s.tpz * z; ++idx;
        };
        seg(conv_w, cm1b,         256, 256,  4, 256 * 256,  1280 * 256);
        seg(mlp1_w, cm1b + 65536, 256, 1024, 4, 256 * 1024, 1280 * 256);
        seg(qkv_w,  qkvb,  256, 768,  4, 256 * 768,  768 * 256);
        seg(proj_w, projb, 256, 256,  4, 256 * 256,  256 * 256);
        seg(mlp2_w, mlp2b, 1024, 256, 4, 1024 * 256, 256 * 1024);
        seg(h1_w, h1b, 256, 2048, 1, 0, 0);
        seg(h2_w, h2b, 2048, 256, 1, 0, 0);
        seg(h3_w, h3b, 256, 2048, 1, 0, 0);
        seg(pr_w, prb, 2048, 512, 1, 0, 0);
        tab.cum[9] = c;
        setup_kernel<<<c + RTOK, 256, 0, stream>>>(
            tab, x, mask_index, Wp, bp, cls, F[0], Fb[0]);
    }

    // ---- 4 block iterations ----
    for (int j = 0; j < 4; ++j) {
        const float* xl = F[j];
        const unsigned short* xlb = Fb[j];
        // union: cm1 GEMM (O1 = gelu conv, MIDU = gelu mlp1) + chanattn MIX init
        cm1chan_kernel<<<640 + RTOK, 256, 0, stream>>>(
            xlb, cm1b + (size_t)j * 1280 * 256, conv_b + j * 256, mlp1_b + j * 1024,
            O1, MIDU,
            xl, F[0], F[1], F[2],
            ca1_w + (size_t)j * 256 * 16, ca1_b + j * 16,
            ca2_w + (size_t)j * 16 * 256, ca2_b + j * 256,
            node_w + j * 8, 5 + j, MIX);
        // mlp2 finalize: MIX = MIX + w[j+1]*O1 + w[j+4]*(t4@mlp2+b); also MIXb
        gemm_mfma<1, ACT_NONE, false, true, 1, false, 4><<<dim3(4, 64), 256, 0, stream>>>(
            MIDU, mlp2b + (size_t)j * 256 * 1024, mlp2_b + j * 256, nullptr, MIX,
            MIX, MIXb, RTOK, 256, 1024, 0, node_w + j * 8, 5 + j, j + 4, O1, j + 1);
        // qkv -> f16
        gemm_mfma<2, ACT_NONE, false, false, 2, false, 0><<<dim3(12, 32), 256, 0, stream>>>(
            MIXb, qkvb + (size_t)j * 768 * 256, qkv_b + j * 768, nullptr, nullptr,
            nullptr, BIGH, RTOK, 768, 256, 0, nullptr, 0, 0, nullptr, 0);
        attn_prep<<<256, 256, 0, stream>>>(
            BIGH, nq_g + j * 16, nq_b + j * 16, nk_g + j * 16, nk_b + j * 16,
            Qp, Kp, Vp);
        attn_kernel<<<dim3(16, NHEAD, BSZ), 256, 0, stream>>>(Qp, Kp, Vp, AOb);
        // proj + residual(MIX) -> F[j+1]
        gemm_mfma<1, ACT_NONE, true, true, 1, false, 0><<<dim3(4, 64), 256, 0, stream>>>(
            AOb, projb + (size_t)j * 256 * 256, proj_b + j * 256, nullptr, MIX,
            F[j + 1], Fb[j + 1], RTOK, 256, 256, 0, nullptr, 0, 0, nullptr, 0);
    }

    // ---- predict head ----
    ln256_kernel<<<1024, 256, 0, stream>>>(F[4], L0b, ln0_g, ln0_b);
    gemm_mfma<2, ACT_NONE, false, false, 1, false, 0><<<dim3(32, 32), 256, 0, stream>>>(
        L0b, h1b, h1_b, nullptr, nullptr, nullptr, H1b, RTOK, 2048, 256, 0,
        nullptr, 0, 0, nullptr, 0);
    ln2048w_kernel<<<1024, 256, 0, stream>>>(H1b, MIDU, ln1_g, ln1_b);
    gemm_mfma<1, ACT_NONE, false, true, 0, false, 0><<<dim3(4, 64), 256, 0, stream>>>(
        MIDU, h2b, h2_b, nullptr, nullptr, MIX, nullptr, RTOK, 256, 2048, 0,
        nullptr, 0, 0, nullptr, 0);
    ln256_kernel<<<1024, 256, 0, stream>>>(MIX, L2b, ln2_g, ln2_b);
    gemm_mfma<2, ACT_NONE, false, false, 1, false, 0><<<dim3(32, 32), 256, 0, stream>>>(
        L2b, h3b, h3_b, nullptr, nullptr, nullptr, H3b, RTOK, 2048, 256, 0,
        nullptr, 0, 0, nullptr, 0);
    gemm_mfma<1, ACT_NONE, false, true, 0, false, 0><<<dim3(8, 64), 256, 0, stream>>>(
        H3b, prb, pr_b, nullptr, nullptr, out, nullptr, RTOK, 512, 2048, 0,
        nullptr, 0, 0, nullptr, 0);
}

// Round 13
// 650.857 us; speedup vs baseline: 1.0469x; 1.0469x over previous
//
#include <hip/hip_runtime.h>
#include <math.h>
#include <cstddef>

// ---- problem constants ----
#define RTOK 4096
#define CDIM 256
#define NHEAD 16
#define DHEAD 16
#define SEQ 1024
#define BSZ 4

#define ACT_NONE 0
#define ACT_GELU 1

typedef short short8 __attribute__((ext_vector_type(8)));
typedef float f32x4  __attribute__((ext_vector_type(4)));
typedef _Float16 half8 __attribute__((ext_vector_type(8)));
typedef _Float16 half4 __attribute__((ext_vector_type(4)));

__device__ __forceinline__ float gelu_erf(float x) {
    return 0.5f * x * (1.0f + erff(x * 0.70710678118654752f));
}
__device__ __forceinline__ unsigned short f2b(float f) {
    unsigned u = __float_as_uint(f);
    unsigned r = (u + 0x7FFFu + ((u >> 16) & 1u)) >> 16;
    return (unsigned short)r;
}
__device__ __forceinline__ float b2f(unsigned short u) {
    return __uint_as_float((unsigned)u << 16);
}
// async global->LDS, 16B per lane. LDS dest must be wave-uniform base + lane*16.
__device__ __forceinline__ void gld16(const unsigned short* g, unsigned short* l) {
    __builtin_amdgcn_global_load_lds(
        (const __attribute__((address_space(1))) unsigned int*)g,
        (__attribute__((address_space(3))) unsigned int*)l, 16, 0, 0);
}
// node-mix softmax weight widx of node_w[0:cnt]/0.01
__device__ __forceinline__ float node_wsel(const float* nwp, int cnt, int widx) {
    float ww[8];
    float mx = -1e30f;
    for (int t = 0; t < cnt; ++t) { ww[t] = nwp[t] * 100.0f; mx = fmaxf(mx, ww[t]); }
    float ssum = 0.0f;
    for (int t = 0; t < cnt; ++t) { ww[t] = expf(ww[t] - mx); ssum += ww[t]; }
    return ww[widx] / ssum;
}

// ---------------------------------------------------------------------------
// Setup union dispatch: weight convert+transpose (9 segments) + patch-embed.
// blocks [0, cum9): wtrans ; blocks [cum9, cum9+4096): embed rows.
// ---------------------------------------------------------------------------
struct WtSeg { const float* in; unsigned short* out; int K, N, ntx, tpz, zin, zout; };
struct WtTab { WtSeg s[9]; int cum[10]; };

__global__ __launch_bounds__(256) void setup_kernel(
    WtTab tab,
    const float* __restrict__ x, const int* __restrict__ mask_index,
    const float* __restrict__ Wp, const float* __restrict__ bp,
    const float* __restrict__ cls,
    float* __restrict__ Fout, unsigned short* __restrict__ Fbout)
{
    __shared__ float tt[32][33];
    __shared__ float xs[12];
    if ((int)blockIdx.x < tab.cum[9]) {
        int g = blockIdx.x;
        int si = 0;
        #pragma unroll
        for (int i = 0; i < 8; ++i) if (g >= tab.cum[i + 1]) si = i + 1;
        WtSeg sg = tab.s[si];
        int t = g - tab.cum[si];
        int z = t / sg.tpz, r = t % sg.tpz;
        int kb = (r % sg.ntx) * 32, nb = (r / sg.ntx) * 32;
        const float* in = sg.in + (size_t)z * sg.zin;
        unsigned short* out = sg.out + (size_t)z * sg.zout;
        int tx = threadIdx.x & 31, ty = threadIdx.x >> 5;   // 32 x 8
        #pragma unroll
        for (int rr = 0; rr < 4; ++rr) {
            int kk = ty * 4 + rr;
            tt[kk][tx] = in[(size_t)(kb + kk) * sg.N + nb + tx];
        }
        __syncthreads();
        #pragma unroll
        for (int rr = 0; rr < 4; ++rr) {
            int nn = ty * 4 + rr;
            out[(size_t)(nb + nn) * sg.K + kb + tx] = f2b(tt[tx][nn]);
        }
    } else {
        int row = blockIdx.x - tab.cum[9];
        int b = row >> 10;
        int c = threadIdx.x;
        int idx = mask_index[row];
        if (idx == 0) {
            float v = cls[c];
            Fout[(size_t)row * 256 + c] = v;
            Fbout[(size_t)row * 256 + c] = f2b(v);
            return;
        }
        int p  = idx - 1;
        int ph = p >> 6, pw = p & 63;
        if (c < 12) {
            int ch = c >> 2, r = (c >> 1) & 1, q = c & 1;
            xs[c] = x[(((size_t)b * 3 + ch) * 128 + (ph * 2 + r)) * 128 + (pw * 2 + q)];
        }
        __syncthreads();
        float acc = bp[c];
        #pragma unroll
        for (int t = 0; t < 12; ++t) acc += xs[t] * Wp[c * 12 + t];
        int part = c >> 6, cc = c & 63;
        double omega = exp((double)cc * -0.14391156831212787);
        double posv  = (part < 2) ? (double)pw : (double)ph;
        double a     = posv * omega;
        double e     = ((part & 1) == 0) ? sin(a) : cos(a);
        float v = acc + (float)e;
        Fout[(size_t)row * 256 + c] = v;
        Fbout[(size_t)row * 256 + c] = f2b(v);
    }
}

// ---------------------------------------------------------------------------
// bf16 MFMA GEMM, BK=64, async global_load_lds(16B) staging into DENSE
// XOR-swizzled LDS, double-buffered (one barrier per 64-K slab). K % 128 == 0.
// XCD-aware block remap.
// BMODE: 0 none, 1 bf16 Cb, 2 f16 Cb.
// SPLIT: col<N0 -> fp32 C side (stride N0, bias), col>=N0 -> Cb bf16.
// NW: 0 none; 2: v = wsel*v + Rsd; 4: v = wsel*v + Rsd + wselB*O1p.
// ---------------------------------------------------------------------------
template<int MT, int ACT, bool RES, bool FOUT, int BMODE, bool SPLIT, int NW>
__global__ __launch_bounds__(256) void gemm_mfma(
    const unsigned short* __restrict__ A, const unsigned short* __restrict__ Bt,
    const float* __restrict__ bias, const float* __restrict__ bias1,
    const float* __restrict__ Rsd,
    float* __restrict__ C, unsigned short* __restrict__ Cb,
    int M, int N, int K, int N0,
    const float* __restrict__ nwp, int ncnt, int widx,
    const float* __restrict__ O1p, int widxB)
{
    constexpr int BM = 64 * MT;
    __shared__ __align__(16) unsigned short As0[BM * 64];
    __shared__ __align__(16) unsigned short As1[BM * 64];
    __shared__ __align__(16) unsigned short Bs0[64 * 64];
    __shared__ __align__(16) unsigned short Bs1[64 * 64];
    int tid = threadIdx.x;
    int w = tid >> 6, lane = tid & 63;
    int l15 = lane & 15, q = lane >> 4;

    int gx = gridDim.x, gy = gridDim.y;
    int L = blockIdx.x + gx * blockIdx.y;
    int xcd = L & 7, j = L >> 3;
    int by = xcd * (gy >> 3) + j / gx;
    int bx = j - (j / gx) * gx;
    int row0 = by * BM, col0 = bx * 64;

    f32x4 acc[MT][4];
    #pragma unroll
    for (int mt = 0; mt < MT; ++mt)
        #pragma unroll
        for (int nt = 0; nt < 4; ++nt)
            acc[mt][nt] = (f32x4){0.f, 0.f, 0.f, 0.f};

#define G_ISSUE(AS, BS, KB)                                                   \
    do {                                                                      \
        _Pragma("unroll")                                                     \
        for (int t = 0; t < 2 * MT; ++t) {                                    \
            int slot = tid + t * 256;                                         \
            int r = slot >> 3;                                                \
            int s = (slot & 7) ^ (r & 7);                                     \
            gld16(A + (size_t)(row0 + r) * K + (KB) + s * 8, &AS[slot * 8]);  \
        }                                                                     \
        _Pragma("unroll")                                                     \
        for (int t = 0; t < 2; ++t) {                                         \
            int slot = tid + t * 256;                                         \
            int r = slot >> 3;                                                \
            int s = (slot & 7) ^ (r & 7);                                     \
            gld16(Bt + (size_t)(col0 + r) * K + (KB) + s * 8, &BS[slot * 8]); \
        }                                                                     \
    } while (0)

#define G_COMPUTE(AS, BS)                                                     \
    do {                                                                      \
        _Pragma("unroll")                                                     \
        for (int hh = 0; hh < 2; ++hh) {                                      \
            short8 af[MT];                                                    \
            _Pragma("unroll")                                                 \
            for (int mt = 0; mt < MT; ++mt) {                                 \
                int R = w * 16 * MT + mt * 16 + l15;                          \
                int c = hh * 4 + q;                                           \
                af[mt] = *(const short8*)&AS[R * 64 + ((c ^ (R & 7)) << 3)];  \
            }                                                                 \
            _Pragma("unroll")                                                 \
            for (int nt = 0; nt < 4; ++nt) {                                  \
                int R = nt * 16 + l15;                                        \
                int c = hh * 4 + q;                                           \
                short8 bf = *(const short8*)&BS[R * 64 + ((c ^ (R & 7)) << 3)];\
                _Pragma("unroll")                                             \
                for (int mt = 0; mt < MT; ++mt)                               \
                    acc[mt][nt] = __builtin_amdgcn_mfma_f32_16x16x32_bf16(    \
                        af[mt], bf, acc[mt][nt], 0, 0, 0);                    \
            }                                                                 \
        }                                                                     \
    } while (0)

    G_ISSUE(As0, Bs0, 0);
    for (int kb = 0; kb < K; kb += 128) {
        __syncthreads();
        G_ISSUE(As1, Bs1, kb + 64);
        G_COMPUTE(As0, Bs0);
        __syncthreads();
        if (kb + 128 < K) G_ISSUE(As0, Bs0, kb + 128);
        G_COMPUTE(As1, Bs1);
    }
#undef G_ISSUE
#undef G_COMPUTE

    float wsel = 0.0f, wselB = 0.0f;
    if (NW > 0) wsel = node_wsel(nwp, ncnt, widx);
    if (NW == 4) wselB = node_wsel(nwp, ncnt, widxB);

    #pragma unroll
    for (int mt = 0; mt < MT; ++mt) {
        #pragma unroll
        for (int nt = 0; nt < 4; ++nt) {
            #pragma unroll
            for (int reg = 0; reg < 4; ++reg) {
                int row = row0 + w * 16 * MT + mt * 16 + q * 4 + reg;
                int col = col0 + nt * 16 + l15;
                if (SPLIT) {
                    float v = acc[mt][nt][reg] +
                              (col < N0 ? bias[col] : bias1[col - N0]);
                    if (ACT == ACT_GELU) v = gelu_erf(v);
                    if (col < N0) C[(size_t)row * N0 + col] = v;
                    else Cb[(size_t)row * (N - N0) + (col - N0)] = f2b(v);
                } else {
                    float v = acc[mt][nt][reg] + bias[col];
                    if (ACT == ACT_GELU) v = gelu_erf(v);
                    if (NW == 2) v = wsel * v + Rsd[(size_t)row * N + col];
                    else if (NW == 4) v = wsel * v + Rsd[(size_t)row * N + col]
                                        + wselB * O1p[(size_t)row * N + col];
                    else if (RES) v += Rsd[(size_t)row * N + col];
                    if (FOUT) C[(size_t)row * N + col] = v;
                    if (BMODE == 1) Cb[(size_t)row * N + col] = f2b(v);
                    if (BMODE == 2) {
                        _Float16 hv = (_Float16)v;
                        Cb[(size_t)row * N + col] = *(unsigned short*)&hv;
                    }
                }
            }
        }
    }
}

// ---------------------------------------------------------------------------
// Channel attention + node-mix init (separate light kernel, ~1.3 KB LDS):
// o2 = sigmoid(relu(xl@ca1+b1)@ca2+b2) * xl
// MIX = sum_{t<j} w[t]*F[t] + (w[j]+w[j+3])*xl + w[j+2]*o2
// (w[j+1]*o1 and w[j+4]*o4 are added in mlp2's NW=4 epilogue)
// ---------------------------------------------------------------------------
__global__ __launch_bounds__(256) void chanattn_kernel(
    const float* __restrict__ xl,
    const float* f0, const float* f1, const float* f2,
    const float* __restrict__ ca1w, const float* __restrict__ ca1b,
    const float* __restrict__ ca2w, const float* __restrict__ ca2b,
    const float* __restrict__ node_w, int cnt,
    float* __restrict__ MIX)
{
    __shared__ float xs[256];
    __shared__ float sm16[16];
    size_t row = blockIdx.x;
    int tid = threadIdx.x;
    xs[tid] = xl[row * 256 + tid];
    __syncthreads();

    int h = tid >> 4, part = tid & 15;
    float p = 0.f;
    #pragma unroll
    for (int i = 0; i < 16; ++i)
        p += xs[part * 16 + i] * ca1w[(part * 16 + i) * 16 + h];
    p += __shfl_down(p, 8, 16);
    p += __shfl_down(p, 4, 16);
    p += __shfl_down(p, 2, 16);
    p += __shfl_down(p, 1, 16);
    if (part == 0) sm16[h] = fmaxf(p + ca1b[h], 0.0f);
    __syncthreads();

    float g = ca2b[tid];
    #pragma unroll
    for (int hh = 0; hh < 16; ++hh) g += sm16[hh] * ca2w[hh * 256 + tid];
    g = 1.0f / (1.0f + expf(-g));
    float o2 = g * xs[tid];

    float ww[8];
    float mx = -1e30f;
    for (int t = 0; t < cnt; ++t) { ww[t] = node_w[t] * 100.0f; mx = fmaxf(mx, ww[t]); }
    float ssum = 0.0f;
    for (int t = 0; t < cnt; ++t) { ww[t] = expf(ww[t] - mx); ssum += ww[t]; }
    float inv = 1.0f / ssum;
    int j = cnt - 5;
    float acc = (ww[j] + ww[j + 3]) * inv * xs[tid] + ww[j + 2] * inv * o2;
    const float* fs[3] = {f0, f1, f2};
    for (int t = 0; t < j; ++t) acc += ww[t] * inv * fs[t][row * 256 + tid];
    MIX[row * 256 + tid] = acc;
}

// ---------------------------------------------------------------------------
// LayerNorm N=256, one WAVE per row (4 rows/block). fp32->bf16.
// ---------------------------------------------------------------------------
__global__ __launch_bounds__(256) void ln256_kernel(
    const float* __restrict__ in, unsigned short* __restrict__ outb,
    const float* __restrict__ g, const float* __restrict__ bb)
{
    int row = blockIdx.x * 4 + (threadIdx.x >> 6);
    int lane = threadIdx.x & 63;
    f32x4 xv = *(const f32x4*)(in + (size_t)row * 256 + lane * 4);
    float s = xv[0] + xv[1] + xv[2] + xv[3];
    #pragma unroll
    for (int off = 1; off < 64; off <<= 1) s += __shfl_xor(s, off, 64);
    float mu = s * (1.0f / 256.0f);
    float d0 = xv[0]-mu, d1 = xv[1]-mu, d2 = xv[2]-mu, d3 = xv[3]-mu;
    float s2 = d0*d0 + d1*d1 + d2*d2 + d3*d3;
    #pragma unroll
    for (int off = 1; off < 64; off <<= 1) s2 += __shfl_xor(s2, off, 64);
    float rstd = rsqrtf(s2 * (1.0f / 256.0f) + 1e-5f);
    f32x4 gv = *(const f32x4*)(g + lane * 4);
    f32x4 bv = *(const f32x4*)(bb + lane * 4);
    ushort4 o;
    o.x = f2b(d0 * rstd * gv[0] + bv[0]);
    o.y = f2b(d1 * rstd * gv[1] + bv[1]);
    o.z = f2b(d2 * rstd * gv[2] + bv[2]);
    o.w = f2b(d3 * rstd * gv[3] + bv[3]);
    *(ushort4*)(outb + (size_t)row * 256 + lane * 4) = o;
}

// ---------------------------------------------------------------------------
// LayerNorm N=2048, one WAVE per row (4 rows/block), bf16->bf16, vectorized.
// ---------------------------------------------------------------------------
__global__ __launch_bounds__(256) void ln2048w_kernel(
    const unsigned short* __restrict__ in, unsigned short* __restrict__ outb,
    const float* __restrict__ g, const float* __restrict__ bb)
{
    int row = blockIdx.x * 4 + (threadIdx.x >> 6);
    int lane = threadIdx.x & 63;
    const unsigned short* xr = in + (size_t)row * 2048 + lane * 32;
    unsigned short v[32];
    *(uint4*)&v[0]  = *(const uint4*)&xr[0];
    *(uint4*)&v[8]  = *(const uint4*)&xr[8];
    *(uint4*)&v[16] = *(const uint4*)&xr[16];
    *(uint4*)&v[24] = *(const uint4*)&xr[24];
    float s = 0.f;
    #pragma unroll
    for (int i = 0; i < 32; ++i) s += b2f(v[i]);
    #pragma unroll
    for (int off = 1; off < 64; off <<= 1) s += __shfl_xor(s, off, 64);
    float mu = s * (1.0f / 2048.0f);
    float s2 = 0.f;
    #pragma unroll
    for (int i = 0; i < 32; ++i) { float d = b2f(v[i]) - mu; s2 += d * d; }
    #pragma unroll
    for (int off = 1; off < 64; off <<= 1) s2 += __shfl_xor(s2, off, 64);
    float rstd = rsqrtf(s2 * (1.0f / 2048.0f) + 1e-5f);
    unsigned short o[32];
    #pragma unroll
    for (int i = 0; i < 32; ++i)
        o[i] = f2b((b2f(v[i]) - mu) * rstd * g[lane * 32 + i] + bb[lane * 32 + i]);
    unsigned short* op = outb + (size_t)row * 2048 + lane * 32;
    *(uint4*)&op[0]  = *(const uint4*)&o[0];
    *(uint4*)&op[8]  = *(const uint4*)&o[8];
    *(uint4*)&op[16] = *(const uint4*)&o[16];
    *(uint4*)&op[24] = *(const uint4*)&o[24];
}

// ---------------------------------------------------------------------------
// Attention prep: LN Q (x scale x log2e) and K once; transpose V.
// Qp/Kp: [bh][tok][16] f16 ; Vp: [bh][d][1024] f16.
// ---------------------------------------------------------------------------
__global__ __launch_bounds__(256) void attn_prep(
    const unsigned short* __restrict__ qkvh,
    const float* __restrict__ nqg, const float* __restrict__ nqb,
    const float* __restrict__ nkg, const float* __restrict__ nkb,
    unsigned short* __restrict__ Qph, unsigned short* __restrict__ Kph,
    unsigned short* __restrict__ Vph)
{
    int b = blockIdx.x >> 6;
    int tokbase = (blockIdx.x & 63) * 16;
    int tid = threadIdx.x;
    int tl = tid >> 4, h = tid & 15;
    int tok = tokbase + tl;
    const _Float16* qkv = (const _Float16*)qkvh;
    const _Float16* rowp = qkv + ((size_t)(b * 1024 + tok)) * 768;
    _Float16* Qp = (_Float16*)Qph;
    _Float16* Kp = (_Float16*)Kph;
    _Float16* Vp = (_Float16*)Vph;
    const float QSC = 0.25f * 1.44269504088896340736f;  // 1/sqrt(16)*log2(e)

    __shared__ _Float16 vt[16][16][17];   // [tok][h][d]

    {
        half8 a0 = *(const half8*)(rowp + h * 16);
        half8 a1 = *(const half8*)(rowp + h * 16 + 8);
        float v[16];
        #pragma unroll
        for (int e = 0; e < 8; ++e) { v[e] = (float)a0[e]; v[8 + e] = (float)a1[e]; }
        float mu = 0.f;
        #pragma unroll
        for (int d = 0; d < 16; ++d) mu += v[d];
        mu *= (1.0f / 16.0f);
        float var = 0.f;
        #pragma unroll
        for (int d = 0; d < 16; ++d) { float t = v[d] - mu; var += t * t; }
        var *= (1.0f / 16.0f);
        float rstd = rsqrtf(var + 1e-5f);
        half8 o0, o1;
        #pragma unroll
        for (int e = 0; e < 8; ++e) {
            o0[e] = (_Float16)(((v[e] - mu) * rstd * nqg[e] + nqb[e]) * QSC);
            o1[e] = (_Float16)(((v[8+e] - mu) * rstd * nqg[8+e] + nqb[8+e]) * QSC);
        }
        _Float16* qo = Qp + ((size_t)(b * 16 + h) * 1024 + tok) * 16;
        *(half8*)qo = o0;
        *(half8*)(qo + 8) = o1;
    }
    {
        half8 a0 = *(const half8*)(rowp + 256 + h * 16);
        half8 a1 = *(const half8*)(rowp + 256 + h * 16 + 8);
        float v[16];
        #pragma unroll
        for (int e = 0; e < 8; ++e) { v[e] = (float)a0[e]; v[8 + e] = (float)a1[e]; }
        float mu = 0.f;
        #pragma unroll
        for (int d = 0; d < 16; ++d) mu += v[d];
        mu *= (1.0f / 16.0f);
        float var = 0.f;
        #pragma unroll
        for (int d = 0; d < 16; ++d) { float t = v[d] - mu; var += t * t; }
        var *= (1.0f / 16.0f);
        float rstd = rsqrtf(var + 1e-5f);
        half8 o0, o1;
        #pragma unroll
        for (int e = 0; e < 8; ++e) {
            o0[e] = (_Float16)((v[e] - mu) * rstd * nkg[e] + nkb[e]);
            o1[e] = (_Float16)((v[8+e] - mu) * rstd * nkg[8+e] + nkb[8+e]);
        }
        _Float16* ko = Kp + ((size_t)(b * 16 + h) * 1024 + tok) * 16;
        *(half8*)ko = o0;
        *(half8*)(ko + 8) = o1;
    }
    {
        half8 a0 = *(const half8*)(rowp + 512 + h * 16);
        half8 a1 = *(const half8*)(rowp + 512 + h * 16 + 8);
        #pragma unroll
        for (int e = 0; e < 8; ++e) { vt[tl][h][e] = a0[e]; vt[tl][h][8 + e] = a1[e]; }
    }
    __syncthreads();
    {
        int h2 = tid >> 4, d = tid & 15;
        half8 o0, o1;
        #pragma unroll
        for (int t = 0; t < 8; ++t) { o0[t] = vt[t][h2][d]; o1[t] = vt[8 + t][h2][d]; }
        _Float16* vo = Vp + ((size_t)(b * 16 + h2) * 16 + d) * 1024 + tokbase;
        *(half8*)vo = o0;
        *(half8*)(vo + 8) = o1;
    }
}

// ---------------------------------------------------------------------------
// MFMA flash attention v4: K/V double-buffered (one barrier per kt), QK^T via
// mfma_f32_16x16x16_f16 (K=16 exactly -> no zero pads), PV via 16x16x32.
// 64-query blocks (grid 16x16x4), 4 waves x 16 q. LDS ~35.5 KB -> 4 blk/CU.
// ---------------------------------------------------------------------------
__global__ __launch_bounds__(256) void attn_kernel(
    const unsigned short* __restrict__ Qph, const unsigned short* __restrict__ Kph,
    const unsigned short* __restrict__ Vph,
    unsigned short* __restrict__ outb)          // [4096,256] bf16
{
    int qt = blockIdx.x, h = blockIdx.y, b = blockIdx.z;
    int bh = b * 16 + h;
    int tid = threadIdx.x;
    int w = tid >> 6, lane = tid & 63;
    int l15 = lane & 15, quad = lane >> 4;
    const _Float16* Qp = (const _Float16*)Qph + (size_t)bh * 1024 * 16;
    const _Float16* Kp = (const _Float16*)Kph + (size_t)bh * 1024 * 16;
    const _Float16* Vp = (const _Float16*)Vph + (size_t)bh * 16 * 1024;

    __shared__ __align__(16) _Float16 Qs[64 * 16];
    __shared__ __align__(16) _Float16 Kb[2][128 * 16];
    __shared__ __align__(16) _Float16 Vt[2][16 * 136];
    __shared__ __align__(16) _Float16 Ps[4][16 * 136];

    // stage Q (64 rows x 16 halves, dense)
    if (tid < 128) {
        int r = tid >> 1, part = tid & 1;
        *(uint4*)&Qs[r * 16 + part * 8] =
            *(const uint4*)(Qp + (size_t)(qt * 64 + r) * 16 + part * 8);
    }

    uint4 r0, r1;
#define A_LOAD(KT)                                                            \
    do {                                                                      \
        if (tid < 128) {                                                      \
            const uint4* src = (const uint4*)(Kp + (size_t)((KT) * 128 + tid) * 16); \
            r0 = src[0]; r1 = src[1];                                         \
        } else {                                                              \
            int t = tid - 128, d = t >> 3, k8 = t & 7;                        \
            const uint4* src = (const uint4*)(Vp + (size_t)d * 1024 + (KT) * 128 + k8 * 16); \
            r0 = src[0]; r1 = src[1];                                         \
        }                                                                     \
    } while (0)
#define A_WRITE(BUF)                                                          \
    do {                                                                      \
        if (tid < 128) {                                                      \
            *(uint4*)&Kb[BUF][tid * 16 + 0] = r0;                             \
            *(uint4*)&Kb[BUF][tid * 16 + 8] = r1;                             \
        } else {                                                              \
            int t = tid - 128, d = t >> 3, k8 = t & 7;                        \
            *(uint4*)&Vt[BUF][d * 136 + k8 * 16 + 0] = r0;                    \
            *(uint4*)&Vt[BUF][d * 136 + k8 * 16 + 8] = r1;                    \
        }                                                                     \
    } while (0)

    A_LOAD(0);
    A_WRITE(0);
    __syncthreads();                // Qs + buf0 visible

    half4 bq = *(const half4*)&Qs[(w * 16 + l15) * 16 + quad * 4];
    float mst = -1e30f, lst = 0.f;
    f32x4 acco = (f32x4){0.f, 0.f, 0.f, 0.f};

    int p = 0;
    for (int kt = 0; kt < 8; ++kt) {
        if (kt < 7) A_LOAD(kt + 1);
        if (kt > 0) __syncthreads();   // buf[p] writes visible; readers of buf[1-p] done

        // ---- S^T tile: 128 keys x 16 queries per wave (K=16 exact) ----
        f32x4 sacc[8];
        #pragma unroll
        for (int ni = 0; ni < 8; ++ni) {
            half4 ak = *(const half4*)&Kb[p][(ni * 16 + l15) * 16 + quad * 4];
            sacc[ni] = __builtin_amdgcn_mfma_f32_16x16x16f16(
                ak, bq, (f32x4){0.f, 0.f, 0.f, 0.f}, 0, 0, 0);
        }
        half8 bv[4];
        #pragma unroll
        for (int c = 0; c < 4; ++c)
            bv[c] = *(const half8*)&Vt[p][l15 * 136 + c * 32 + quad * 8];

        // ---- online softmax for the wave's 16 queries (q = l15) ----
        float rm = sacc[0][0];
        #pragma unroll
        for (int ni = 0; ni < 8; ++ni)
            #pragma unroll
            for (int reg = 0; reg < 4; ++reg)
                rm = fmaxf(rm, sacc[ni][reg]);
        rm = fmaxf(rm, __shfl_xor(rm, 16, 64));
        rm = fmaxf(rm, __shfl_xor(rm, 32, 64));
        float mn  = fmaxf(mst, rm);
        float cor = exp2f(mst - mn);
        mst = mn;
        lst *= cor;
        #pragma unroll
        for (int reg = 0; reg < 4; ++reg) {
            float cR = __shfl(cor, (lane & 48) + quad * 4 + reg, 64);
            acco[reg] *= cR;
        }
        float lsum = 0.f;
        #pragma unroll
        for (int ni = 0; ni < 8; ++ni) {
            half4 ph;
            #pragma unroll
            for (int reg = 0; reg < 4; ++reg) {
                float pp = exp2f(sacc[ni][reg] - mn);
                lsum += pp;
                ph[reg] = (_Float16)pp;
            }
            *(half4*)&Ps[w][l15 * 136 + ni * 16 + quad * 4] = ph;
        }
        lsum += __shfl_xor(lsum, 16, 64);
        lsum += __shfl_xor(lsum, 32, 64);
        lst += lsum;

        // ---- PV (Ps wave-private; 16x16x32) ----
        #pragma unroll
        for (int c = 0; c < 4; ++c) {
            half8 p0 = *(const half8*)&Ps[w][l15 * 136 + c * 32 + quad * 8];
            acco = __builtin_amdgcn_mfma_f32_16x16x32_f16(p0, bv[c], acco, 0, 0, 0);
        }

        if (kt < 7) A_WRITE(1 - p);
        p ^= 1;
    }
#undef A_LOAD
#undef A_WRITE

    #pragma unroll
    for (int reg = 0; reg < 4; ++reg) {
        float lR = __shfl(lst, (lane & 48) + quad * 4 + reg, 64);
        float o = acco[reg] / lR;
        int row = b * 1024 + qt * 64 + w * 16 + quad * 4 + reg;
        outb[(size_t)row * 256 + h * 16 + l15] = f2b(o);
    }
}

// ---------------------------------------------------------------------------
extern "C" void kernel_launch(void* const* d_in, const int* in_sizes, int n_in,
                              void* d_out, int out_size, void* d_ws, size_t ws_size,
                              hipStream_t stream)
{
    const float* x          = (const float*)d_in[0];
    const int*   mask_index = (const int*)  d_in[1];
    const float* Wp         = (const float*)d_in[2];
    const float* bp         = (const float*)d_in[3];
    const float* cls        = (const float*)d_in[4];
    const float* qkv_w      = (const float*)d_in[5];
    const float* qkv_b      = (const float*)d_in[6];
    const float* proj_w     = (const float*)d_in[7];
    const float* proj_b     = (const float*)d_in[8];
    const float* nq_g       = (const float*)d_in[9];
    const float* nq_b       = (const float*)d_in[10];
    const float* nk_g       = (const float*)d_in[11];
    const float* nk_b       = (const float*)d_in[12];
    const float* conv_w     = (const float*)d_in[13];
    const float* conv_b     = (const float*)d_in[14];
    const float* ca1_w      = (const float*)d_in[15];
    const float* ca1_b      = (const float*)d_in[16];
    const float* ca2_w      = (const float*)d_in[17];
    const float* ca2_b      = (const float*)d_in[18];
    const float* mlp1_w     = (const float*)d_in[19];
    const float* mlp1_b     = (const float*)d_in[20];
    const float* mlp2_w     = (const float*)d_in[21];
    const float* mlp2_b     = (const float*)d_in[22];
    const float* node_w     = (const float*)d_in[23];
    const float* ln0_g      = (const float*)d_in[24];
    const float* ln0_b      = (const float*)d_in[25];
    const float* h1_w       = (const float*)d_in[26];
    const float* h1_b       = (const float*)d_in[27];
    const float* ln1_g      = (const float*)d_in[28];
    const float* ln1_b      = (const float*)d_in[29];
    const float* h2_w       = (const float*)d_in[30];
    const float* h2_b       = (const float*)d_in[31];
    const float* ln2_g      = (const float*)d_in[32];
    const float* ln2_b      = (const float*)d_in[33];
    const float* h3_w       = (const float*)d_in[34];
    const float* h3_b       = (const float*)d_in[35];
    const float* pr_w       = (const float*)d_in[36];
    const float* pr_b       = (const float*)d_in[37];
    float* out = (float*)d_out;

    // ---- workspace layout ----
    char* base = (char*)d_ws;
    size_t off = 0;
    auto alloc = [&](size_t bytes) -> char* {
        char* p = base + off;
        off += (bytes + 255) & ~(size_t)255;
        return p;
    };
    const size_t RC = (size_t)RTOK * CDIM;
    float* F[5];
    unsigned short* Fb[5];
    for (int i = 0; i < 5; ++i) F[i] = (float*)alloc(RC * 4);
    for (int i = 0; i < 5; ++i) Fb[i] = (unsigned short*)alloc(RC * 2);
    float* MIX = (float*)alloc(RC * 4);
    float* O1  = (float*)alloc(RC * 4);
    unsigned short* MIXb = (unsigned short*)alloc(RC * 2);
    unsigned short* AOb  = (unsigned short*)alloc(RC * 2);
    unsigned short* BIGH = (unsigned short*)alloc((size_t)RTOK * 768 * 2);  // qkv f16
    unsigned short* Qp   = (unsigned short*)alloc(RC * 2);
    unsigned short* Kp   = (unsigned short*)alloc(RC * 2);
    unsigned short* Vp   = (unsigned short*)alloc(RC * 2);
    unsigned short* H1b  = (unsigned short*)alloc((size_t)RTOK * 2048 * 2);
    unsigned short* MIDU = (unsigned short*)alloc((size_t)RTOK * 2048 * 2);
    unsigned short* L0b  = (unsigned short*)alloc(RC * 2);
    unsigned short* L2b  = (unsigned short*)alloc(RC * 2);
    unsigned short* H3b  = (unsigned short*)alloc((size_t)RTOK * 2048 * 2);
    // bf16 transposed weights; conv||mlp1 concatenated to [1280,256] per layer
    unsigned short* cm1b  = (unsigned short*)alloc((size_t)4 * 1280 * 256 * 2);
    unsigned short* qkvb  = (unsigned short*)alloc((size_t)4 * 768 * 256 * 2);
    unsigned short* projb = (unsigned short*)alloc((size_t)4 * 256 * 256 * 2);
    unsigned short* mlp2b = (unsigned short*)alloc((size_t)4 * 256 * 1024 * 2);
    unsigned short* h1b   = (unsigned short*)alloc((size_t)2048 * 256 * 2);
    unsigned short* h2b   = (unsigned short*)alloc((size_t)256 * 2048 * 2);
    unsigned short* h3b   = (unsigned short*)alloc((size_t)2048 * 256 * 2);
    unsigned short* prb   = (unsigned short*)alloc((size_t)512 * 2048 * 2);

    // ---- setup: weight conversion + embed in ONE dispatch ----
    {
        WtTab tab;
        int c = 0, idx = 0;
        auto seg = [&](const float* in, unsigned short* outp, int K, int N,
                       int z, int zin, int zout) {
            WtSeg s; s.in = in; s.out = outp; s.K = K; s.N = N;
            s.ntx = K / 32; s.tpz = (K / 32) * (N / 32);
            s.zin = zin; s.zout = zout;
            tab.s[idx] = s; tab.cum[idx] = c;
            c += s.tpz * z; ++idx;
        };
        seg(conv_w, cm1b,         256, 256,  4, 256 * 256,  1280 * 256);
        seg(mlp1_w, cm1b + 65536, 256, 1024, 4, 256 * 1024, 1280 * 256);
        seg(qkv_w,  qkvb,  256, 768,  4, 256 * 768,  768 * 256);
        seg(proj_w, projb, 256, 256,  4, 256 * 256,  256 * 256);
        seg(mlp2_w, mlp2b, 1024, 256, 4, 1024 * 256, 256 * 1024);
        seg(h1_w, h1b, 256, 2048, 1, 0, 0);
        seg(h2_w, h2b, 2048, 256, 1, 0, 0);
        seg(h3_w, h3b, 256, 2048, 1, 0, 0);
        seg(pr_w, prb, 2048, 512, 1, 0, 0);
        tab.cum[9] = c;
        setup_kernel<<<c + RTOK, 256, 0, stream>>>(
            tab, x, mask_index, Wp, bp, cls, F[0], Fb[0]);
    }

    // ---- 4 block iterations ----
    for (int j = 0; j < 4; ++j) {
        const float* xl = F[j];
        const unsigned short* xlb = Fb[j];
        // cm1 GEMM: O1 = gelu(xl@conv+b) fp32 ; MIDU = gelu(xl@mlp1+b) bf16
        gemm_mfma<2, ACT_GELU, false, false, 0, true, 0><<<dim3(20, 32), 256, 0, stream>>>(
            xlb, cm1b + (size_t)j * 1280 * 256, conv_b + j * 256, mlp1_b + j * 1024,
            nullptr, O1, MIDU, RTOK, 1280, 256, 256, nullptr, 0, 0, nullptr, 0);
        // chanattn + node-mix init (light, high-occupancy)
        chanattn_kernel<<<RTOK, 256, 0, stream>>>(
            xl, F[0], F[1], F[2],
            ca1_w + (size_t)j * 256 * 16, ca1_b + j * 16,
            ca2_w + (size_t)j * 16 * 256, ca2_b + j * 256,
            node_w + j * 8, 5 + j, MIX);
        // mlp2 finalize: MIX = MIX + w[j+1]*O1 + w[j+4]*(t4@mlp2+b); also MIXb
        gemm_mfma<1, ACT_NONE, false, true, 1, false, 4><<<dim3(4, 64), 256, 0, stream>>>(
            MIDU, mlp2b + (size_t)j * 256 * 1024, mlp2_b + j * 256, nullptr, MIX,
            MIX, MIXb, RTOK, 256, 1024, 0, node_w + j * 8, 5 + j, j + 4, O1, j + 1);
        // qkv -> f16
        gemm_mfma<2, ACT_NONE, false, false, 2, false, 0><<<dim3(12, 32), 256, 0, stream>>>(
            MIXb, qkvb + (size_t)j * 768 * 256, qkv_b + j * 768, nullptr, nullptr,
            nullptr, BIGH, RTOK, 768, 256, 0, nullptr, 0, 0, nullptr, 0);
        attn_prep<<<256, 256, 0, stream>>>(
            BIGH, nq_g + j * 16, nq_b + j * 16, nk_g + j * 16, nk_b + j * 16,
            Qp, Kp, Vp);
        attn_kernel<<<dim3(16, NHEAD, BSZ), 256, 0, stream>>>(Qp, Kp, Vp, AOb);
        // proj + residual(MIX) -> F[j+1]
        gemm_mfma<1, ACT_NONE, true, true, 1, false, 0><<<dim3(4, 64), 256, 0, stream>>>(
            AOb, projb + (size_t)j * 256 * 256, proj_b + j * 256, nullptr, MIX,
            F[j + 1], Fb[j + 1], RTOK, 256, 256, 0, nullptr, 0, 0, nullptr, 0);
    }

    // ---- predict head ----
    ln256_kernel<<<1024, 256, 0, stream>>>(F[4], L0b, ln0_g, ln0_b);
    gemm_mfma<2, ACT_NONE, false, false, 1, false, 0><<<dim3(32, 32), 256, 0, stream>>>(
        L0b, h1b, h1_b, nullptr, nullptr, nullptr, H1b, RTOK, 2048, 256, 0,
        nullptr, 0, 0, nullptr, 0);
    ln2048w_kernel<<<1024, 256, 0, stream>>>(H1b, MIDU, ln1_g, ln1_b);
    gemm_mfma<1, ACT_NONE, false, true, 0, false, 0><<<dim3(4, 64), 256, 0, stream>>>(
        MIDU, h2b, h2_b, nullptr, nullptr, MIX, nullptr, RTOK, 256, 2048, 0,
        nullptr, 0, 0, nullptr, 0);
    ln256_kernel<<<1024, 256, 0, stream>>>(MIX, L2b, ln2_g, ln2_b);
    gemm_mfma<2, ACT_NONE, false, false, 1, false, 0><<<dim3(32, 32), 256, 0, stream>>>(
        L2b, h3b, h3_b, nullptr, nullptr, nullptr, H3b, RTOK, 2048, 256, 0,
        nullptr, 0, 0, nullptr, 0);
    gemm_mfma<1, ACT_NONE, false, true, 0, false, 0><<<dim3(8, 64), 256, 0, stream>>>(
        H3b, prb, pr_b, nullptr, nullptr, out, nullptr, RTOK, 512, 2048, 0,
        nullptr, 0, 0, nullptr, 0);
}